// Round 5
// baseline (85.659 us; speedup 1.0000x reference)
//
#include <hip/hip_runtime.h>

#define NTHREADS 256
#define N_ATOMS 1024
#define HIDDEN 64

// REVERT to the round-2 winner (83.6 us measured): one block per PAIR of
// atoms (grid = B*N/2 = 4096), 256 threads, ~18.6 KB LDS -> 8 blocks/CU.
// Round-3/4 established that 4-atom batching loses even at equal occupancy
// (85.5 vs 83.6): the wave-0 MLP tail is latency-bound on its serial
// ds_read->fma chain, so doubling per-block tail length while halving the
// number of independent tails is a net loss. 2 atoms/block is the empirical
// optimum of the amortization-vs-parallelism trade.
// Remaining measurement: ~80.5 us harness poison-fill floor (2 x 40.2 us at
// ~84% HBM peak) + ~3.0 us kernel residual (~structural floor).
__global__ __launch_bounds__(NTHREADS) void LocalFeatureEncoder_40063454937486_kernel(
    const float* __restrict__ pos,    // [B,N,3]
    const int*   __restrict__ types,  // [B,N]
    const float* __restrict__ W1,     // [34,64]
    const float* __restrict__ b1,     // [64]
    const float* __restrict__ W2,     // [64,64]
    const float* __restrict__ b2,     // [64]
    const float* __restrict__ W3,     // [64,64]
    const float* __restrict__ b3,     // [64]
    float*       __restrict__ out)    // [B,N,64]
{
    const int blk  = blockIdx.x;          // bidx*512 + pair
    const int bidx = blk >> 9;            // 512 pairs per batch
    const int i0   = (blk & 511) * 2;
    const int i1   = i0 + 1;
    const int tid  = threadIdx.x;
    const int lane = tid & 63;
    const int wav  = tid >> 6;

    __shared__ __align__(16) float qd[2][N_ATOMS];   // queue: distance
    __shared__ __align__(16) float qm[2][N_ATOMS];   // queue: +cutv type0 / -cutv type1
    __shared__ __align__(16) float partial[4 * 64];  // [wav][f=2r+s][atom]
    __shared__ __align__(16) float feats[34 * 2];    // [k][atom]
    __shared__ __align__(16) float h1s[HIDDEN * 2];  // [k][atom]
    __shared__ __align__(16) float h2s[HIDDEN * 2];  // [k][atom]
    __shared__ int cnt;                               // packed: n0 | n1<<16

    const float* pf   = pos + (size_t)bidx * (N_ATOMS * 3);
    const int*   typb = types + (size_t)bidx * N_ATOMS;

    // ---- issue all neighbor loads BEFORE the barrier (latency overlap) ----
    const float4 p0 = *(const float4*)(pf + tid * 12);
    const float4 p1 = *(const float4*)(pf + tid * 12 + 4);
    const float4 p2 = *(const float4*)(pf + tid * 12 + 8);
    const int4   tv = *(const int4*)(typb + tid * 4);

    const float xi0 = pf[i0 * 3 + 0], yi0 = pf[i0 * 3 + 1], zi0 = pf[i0 * 3 + 2];
    const float xi1 = pf[i1 * 3 + 0], yi1 = pf[i1 * 3 + 1], zi1 = pf[i1 * 3 + 2];

    if (tid == 0) cnt = 0;
    __syncthreads();                      // cnt = 0 visible

    // ---------- phase 1a: distances + compaction for BOTH atoms ----------
    {
        const float px[4] = {p0.x, p0.w, p1.z, p2.y};
        const float py[4] = {p0.y, p1.x, p1.w, p2.z};
        const float pz[4] = {p0.z, p1.y, p2.x, p2.w};
        const int   tj[4] = {tv.x, tv.y, tv.z, tv.w};

        float sq0[4], sq1[4];
        bool  pr0[4], pr1[4];
        unsigned long long m0[4], m1[4];
#pragma unroll
        for (int q = 0; q < 4; ++q) {
            const int j = tid * 4 + q;
            float dx = xi0 - px[q], dy = yi0 - py[q], dz = zi0 - pz[q];
            sq0[q] = dx * dx + dy * dy + dz * dz;
            dx = xi1 - px[q]; dy = yi1 - py[q]; dz = zi1 - pz[q];
            sq1[q] = dx * dx + dy * dy + dz * dz;
            pr0[q] = (j != i0) && (sq0[q] < 6.25f);
            pr1[q] = (j != i1) && (sq1[q] < 6.25f);
            m0[q]  = __ballot(pr0[q]);
            m1[q]  = __ballot(pr1[q]);
        }

        const int tot0 = (int)(__popcll(m0[0]) + __popcll(m0[1]) +
                               __popcll(m0[2]) + __popcll(m0[3]));
        const int tot1 = (int)(__popcll(m1[0]) + __popcll(m1[1]) +
                               __popcll(m1[2]) + __popcll(m1[3]));
        // single packed atomic: n0 in [15:0], n1 in [31:16] (each sums <= 1024)
        int basep = 0;
        if (lane == 0) basep = atomicAdd(&cnt, tot0 | (tot1 << 16));
        basep = __shfl(basep, 0, 64);     // convergent broadcast

        const unsigned long long lt = (1ull << lane) - 1ull;
        int off0 = basep & 0xffff;
        int off1 = (basep >> 16) & 0xffff;
#pragma unroll
        for (int q = 0; q < 4; ++q) {
            if (pr0[q]) {
                const float d  = sqrtf(sq0[q]);
                const float x  = d * 0.4f;    // d / 2.5
                const float x3 = x * x * x;
                const float cutv = 1.0f + x3 * (-10.0f + x * (15.0f - 6.0f * x));
                const int idx = off0 + (int)__popcll(m0[q] & lt);
                qd[0][idx] = d;
                qm[0][idx] = (tj[q] == 0) ? cutv : -cutv;
            }
            if (pr1[q]) {
                const float d  = sqrtf(sq1[q]);
                const float x  = d * 0.4f;
                const float x3 = x * x * x;
                const float cutv = 1.0f + x3 * (-10.0f + x * (15.0f - 6.0f * x));
                const int idx = off1 + (int)__popcll(m1[q] & lt);
                qd[1][idx] = d;
                qm[1][idx] = (tj[q] == 0) ? cutv : -cutv;
            }
            off0 += (int)__popcll(m0[q]); // wave-uniform prefix for next round
            off1 += (int)__popcll(m1[q]);
        }
    }
    __syncthreads();
    const int packed = cnt;
    const int n0   = packed & 0xffff;
    const int n1   = (packed >> 16) & 0xffff;
    const int nmax = (n0 > n1) ? n0 : n1;

    // ---------- phase 1b: r-parallel RBF accumulation, both atoms ----------
    {
        const int slot = tid >> 4;            // pair slot 0..15
        const int r    = tid & 15;            // RBF center 0..15
        const float c  = (float)r * (2.5f / 15.0f);

        float a00 = 0.0f, a10 = 0.0f;         // a<species><atom>
        float a01 = 0.0f, a11 = 0.0f;
        for (int e = slot; e < nmax; e += 16) {
            if (e < n0) {
                const float d    = qd[0][e];
                const float mm   = qm[0][e];
                const float diff = d - c;
                const float ex   = __expf(-(diff * diff) * 36.0f);
                a00 = fmaf(fmaxf( mm, 0.0f), ex, a00);
                a10 = fmaf(fmaxf(-mm, 0.0f), ex, a10);
            }
            if (e < n1) {
                const float d    = qd[1][e];
                const float mm   = qm[1][e];
                const float diff = d - c;
                const float ex   = __expf(-(diff * diff) * 36.0f);
                a01 = fmaf(fmaxf( mm, 0.0f), ex, a01);
                a11 = fmaf(fmaxf(-mm, 0.0f), ex, a11);
            }
        }
        a00 += __shfl_xor(a00, 16, 64);  a00 += __shfl_xor(a00, 32, 64);
        a10 += __shfl_xor(a10, 16, 64);  a10 += __shfl_xor(a10, 32, 64);
        a01 += __shfl_xor(a01, 16, 64);  a01 += __shfl_xor(a01, 32, 64);
        a11 += __shfl_xor(a11, 16, 64);  a11 += __shfl_xor(a11, 32, 64);
        if (lane < 16) {
            // partial[wav][f][atom], f=2r+s: 4 consecutive floats -> one b128
            const float4 v = {a00, a01, a10, a11};
            *(float4*)&partial[wav * 64 + r * 4] = v;
        }
        if (tid == 0) {
            const int t0 = typb[i0], t1 = typb[i1];
            feats[0] = (t0 == 0) ? 1.0f : 0.0f;   // k=0 (species0), atom0
            feats[1] = (t1 == 0) ? 1.0f : 0.0f;   // k=0, atom1
            feats[2] = (t0 == 1) ? 1.0f : 0.0f;   // k=1 (species1), atom0
            feats[3] = (t1 == 1) ? 1.0f : 0.0f;   // k=1, atom1
        }
    }
    __syncthreads();

    // ---------- wave-0-only tail: finalize feats + 3-layer MLP, 2 atoms ----------
    if (tid < HIDDEN) {
        if (tid < 32) {
            float2 acc      = *(const float2*)&partial[tid * 2];
            const float2 q1 = *(const float2*)&partial[ 64 + tid * 2];
            const float2 q2 = *(const float2*)&partial[128 + tid * 2];
            const float2 q3 = *(const float2*)&partial[192 + tid * 2];
            acc.x += q1.x + q2.x + q3.x;
            acc.y += q1.y + q2.y + q3.y;
            *(float2*)&feats[(2 + tid) * 2] = acc;
        }
        __builtin_amdgcn_wave_barrier();

        float h0 = b1[tid], h1v = b1[tid];
#pragma unroll
        for (int k = 0; k < 34; ++k) {
            const float w  = W1[k * HIDDEN + tid];
            const float2 f = *(const float2*)&feats[k * 2];
            h0  = fmaf(f.x, w, h0);
            h1v = fmaf(f.y, w, h1v);
        }
        h0  = h0  / (1.0f + __expf(-h0));
        h1v = h1v / (1.0f + __expf(-h1v));
        *(float2*)&h1s[tid * 2] = make_float2(h0, h1v);
        __builtin_amdgcn_wave_barrier();

        float g0 = b2[tid], g1 = b2[tid];
#pragma unroll
        for (int k = 0; k < HIDDEN; ++k) {
            const float w  = W2[k * HIDDEN + tid];
            const float2 f = *(const float2*)&h1s[k * 2];
            g0 = fmaf(f.x, w, g0);
            g1 = fmaf(f.y, w, g1);
        }
        g0 = g0 / (1.0f + __expf(-g0));
        g1 = g1 / (1.0f + __expf(-g1));
        *(float2*)&h2s[tid * 2] = make_float2(g0, g1);
        __builtin_amdgcn_wave_barrier();

        float o0 = b3[tid], o1 = b3[tid];
#pragma unroll
        for (int k = 0; k < HIDDEN; ++k) {
            const float w  = W3[k * HIDDEN + tid];
            const float2 f = *(const float2*)&h2s[k * 2];
            o0 = fmaf(f.x, w, o0);
            o1 = fmaf(f.y, w, o1);
        }
        const size_t row0 = (size_t)(bidx * N_ATOMS + i0) * HIDDEN;
        out[row0 + tid]          = o0;
        out[row0 + HIDDEN + tid] = o1;    // i1 = i0+1 -> contiguous row
    }
}

extern "C" void kernel_launch(void* const* d_in, const int* in_sizes, int n_in,
                              void* d_out, int out_size, void* d_ws, size_t ws_size,
                              hipStream_t stream) {
    const float* pos   = (const float*)d_in[0];
    const int*   types = (const int*)d_in[1];
    const float* W1    = (const float*)d_in[2];
    const float* b1    = (const float*)d_in[3];
    const float* W2    = (const float*)d_in[4];
    const float* b2    = (const float*)d_in[5];
    const float* W3    = (const float*)d_in[6];
    const float* b3    = (const float*)d_in[7];
    float*       out   = (float*)d_out;

    const int BN = in_sizes[1];           // B*N = 8192
    const int nblocks = BN >> 1;          // one block per atom pair

    LocalFeatureEncoder_40063454937486_kernel<<<nblocks, NTHREADS, 0, stream>>>(
        pos, types, W1, b1, W2, b2, W3, b3, out);
}